// Round 1
// baseline (558.828 us; speedup 1.0000x reference)
//
#include <hip/hip_runtime.h>
#include <math.h>

// ---------------- CSR build ----------------
__global__ __launch_bounds__(256) void k_hist(const int* __restrict__ dst, int* __restrict__ deg, int E){
  int e = blockIdx.x*256 + threadIdx.x;
  if (e < E) atomicAdd(&deg[dst[e]], 1);
}

__global__ __launch_bounds__(256) void k_scan_local(const int* __restrict__ deg, int* __restrict__ offs,
    int* __restrict__ blksum, int nelem, int ndeg){
  __shared__ int sh[256];
  int t = threadIdx.x;
  int i = blockIdx.x*256 + t;
  int v = (i < ndeg) ? deg[i] : 0;
  sh[t] = v; __syncthreads();
  for (int d = 1; d < 256; d <<= 1){
    int add = (t >= d) ? sh[t-d] : 0; __syncthreads();
    sh[t] += add; __syncthreads();
  }
  if (i < nelem) offs[i] = sh[t] - v;   // exclusive
  if (t == 255) blksum[blockIdx.x] = sh[t];
}

__global__ __launch_bounds__(256) void k_scan_blk(int* __restrict__ blksum, int nb){
  __shared__ int sh[256];
  int t = threadIdx.x;
  int running = 0;
  for (int base = 0; base < nb; base += 256){
    int v = (base+t < nb) ? blksum[base+t] : 0;
    __syncthreads();
    sh[t] = v; __syncthreads();
    for (int d = 1; d < 256; d <<= 1){
      int add = (t >= d) ? sh[t-d] : 0; __syncthreads();
      sh[t] += add; __syncthreads();
    }
    if (base+t < nb) blksum[base+t] = running + sh[t] - v;
    running += sh[255];
  }
}

__global__ __launch_bounds__(256) void k_scan_add(int* __restrict__ offs, const int* __restrict__ blksum, int nelem){
  int i = blockIdx.x*256 + threadIdx.x;
  if (i < nelem) offs[i] += blksum[blockIdx.x];
}

__global__ __launch_bounds__(256) void k_scatter(const int* __restrict__ src, const int* __restrict__ dst,
    const int* __restrict__ offs, int* __restrict__ cursor, int* __restrict__ srcs, int E){
  int e = blockIdx.x*256 + threadIdx.x;
  if (e < E){
    int d = dst[e];
    int pos = offs[d] + atomicAdd(&cursor[d], 1);
    srcs[pos] = src[e];
  }
}

// ---------------- per-layer weight folding ----------------
// watt[j][k] (j<4: src head j, j>=4: dst head j-4) = sum_c W[k, h*64+c]*att[h,c]
// wbig[h*64+kk][c] = 0.25 * W[kk, h*64+c]   (head-mean folded in)
__global__ __launch_bounds__(512) void k_prep(const float* __restrict__ W, const float* __restrict__ att_src,
    const float* __restrict__ att_dst, float* __restrict__ watt, float* __restrict__ wbig){
  int t = threadIdx.x;
  int j = t >> 6, k = t & 63, h = j & 3;
  const float* att = (j < 4) ? att_src : att_dst;
  float s = 0.f;
  for (int c = 0; c < 64; ++c) s += W[k*256 + h*64 + c] * att[h*64 + c];
  watt[j*64 + k] = s;
  for (int i = t; i < 16384; i += 512){
    int hk = i >> 6, c = i & 63;
    int hh = hk >> 6, kk = hk & 63;
    wbig[i] = 0.25f * W[kk*256 + hh*64 + c];
  }
}

// ---------------- attention scalars: a_src/a_dst [N,4] ----------------
__global__ __launch_bounds__(256) void k_att(const float* __restrict__ feat, const float* __restrict__ watt,
    float* __restrict__ asrc, float* __restrict__ adst, int n){
  int tid = blockIdx.x*256 + threadIdx.x;
  if (tid >= n*8) return;
  int v = tid >> 3, j = tid & 7;
  const float4* f = (const float4*)(feat + (size_t)v*64);
  const float4* w = (const float4*)(watt + j*64);
  float s = 0.f;
  #pragma unroll
  for (int k = 0; k < 16; ++k){
    float4 a = f[k], b = w[k];
    s += a.x*b.x + a.y*b.y + a.z*b.z + a.w*b.w;
  }
  if (j < 4) asrc[v*4 + j] = s; else adst[v*4 + (j-4)] = s;
}

// ---------------- linear skip path: lin = feat @ lW + lb ----------------
__global__ __launch_bounds__(256) void k_lin(const float* __restrict__ feat, const float* __restrict__ lW,
    const float* __restrict__ lb, float* __restrict__ lin, int n){
  __shared__ float sW[4096];
  for (int i = threadIdx.x; i < 4096; i += 256) sW[i] = lW[i];
  __syncthreads();
  int lane = threadIdx.x & 63;
  int wid = __builtin_amdgcn_readfirstlane(threadIdx.x >> 6);
  int vb = blockIdx.x*32 + wid*8;
  const float* fp[8];
  #pragma unroll
  for (int j = 0; j < 8; ++j){
    int vj = vb + j; if (vj > n-1) vj = n-1;    // clamp: no OOB, tail discarded below
    fp[j] = feat + (size_t)vj*64;
  }
  float acc[8] = {0,0,0,0,0,0,0,0};
  for (int k4 = 0; k4 < 16; ++k4){
    float w0 = sW[(k4*4+0)*64 + lane];
    float w1 = sW[(k4*4+1)*64 + lane];
    float w2 = sW[(k4*4+2)*64 + lane];
    float w3 = sW[(k4*4+3)*64 + lane];
    #pragma unroll
    for (int j = 0; j < 8; ++j){
      float4 f = *(const float4*)(fp[j] + k4*4);   // wave-uniform -> s_load_dwordx4
      acc[j] = fmaf(f.x, w0, acc[j]);
      acc[j] = fmaf(f.y, w1, acc[j]);
      acc[j] = fmaf(f.z, w2, acc[j]);
      acc[j] = fmaf(f.w, w3, acc[j]);
    }
  }
  float blb = lb[lane];
  #pragma unroll
  for (int j = 0; j < 8; ++j){
    int vj = vb + j;
    if (vj < n) lin[(size_t)vj*64 + lane] = acc[j] + blb;
  }
}

// ---------------- edge aggregation: one wave per dst node, online softmax ----------------
__global__ __launch_bounds__(256) void k_agg(const float* __restrict__ feat, const float* __restrict__ asrc,
    const float* __restrict__ adst, const int* __restrict__ offs, const int* __restrict__ srcs,
    float* __restrict__ accx, int n){
  int wid = __builtin_amdgcn_readfirstlane(threadIdx.x >> 6);
  int lane = threadIdx.x & 63;
  int v = blockIdx.x*4 + wid;
  if (v >= n) return;
  int rs = offs[v], re = offs[v+1];
  float4 ad = *(const float4*)(adst + (size_t)v*4);
  float m0=-INFINITY, m1=-INFINITY, m2=-INFINITY, m3=-INFINITY;
  float s0=0.f, s1=0.f, s2=0.f, s3=0.f;
  float a0=0.f, a1=0.f, a2=0.f, a3=0.f;
  for (int i = rs; i < re; ++i){
    int sid = srcs[i];                                   // uniform -> s_load
    float4 as = *(const float4*)(asrc + (size_t)sid*4);  // uniform -> s_load_dwordx4
    float xk = feat[(size_t)sid*64 + lane];              // 256B coalesced gather
    {
      float l = as.x + ad.x; l = fmaxf(l, 0.2f*l);
      float mn = fmaxf(m0, l);
      float sc = __expf(m0 - mn), p = __expf(l - mn);
      s0 = s0*sc + p; a0 = a0*sc + p*xk; m0 = mn;
    }
    {
      float l = as.y + ad.y; l = fmaxf(l, 0.2f*l);
      float mn = fmaxf(m1, l);
      float sc = __expf(m1 - mn), p = __expf(l - mn);
      s1 = s1*sc + p; a1 = a1*sc + p*xk; m1 = mn;
    }
    {
      float l = as.z + ad.z; l = fmaxf(l, 0.2f*l);
      float mn = fmaxf(m2, l);
      float sc = __expf(m2 - mn), p = __expf(l - mn);
      s2 = s2*sc + p; a2 = a2*sc + p*xk; m2 = mn;
    }
    {
      float l = as.w + ad.w; l = fmaxf(l, 0.2f*l);
      float mn = fmaxf(m3, l);
      float sc = __expf(m3 - mn), p = __expf(l - mn);
      s3 = s3*sc + p; a3 = a3*sc + p*xk; m3 = mn;
    }
  }
  size_t base = (size_t)v*256 + lane;
  accx[base +   0] = a0 / (s0 + 1e-16f);   // deg==0 -> 0/eps = 0, matches segment_sum
  accx[base +  64] = a1 / (s1 + 1e-16f);
  accx[base + 128] = a2 / (s2 + 1e-16f);
  accx[base + 192] = a3 / (s3 + 1e-16f);
}

// ---------------- epilogue: out = accx @ wbig + bias + lin (+relu) ----------------
__global__ __launch_bounds__(256) void k_out(const float* __restrict__ accx, const float* __restrict__ wbig,
    const float* __restrict__ bias, const float* __restrict__ lin, float* __restrict__ outp,
    int n, int do_relu){
  __shared__ float sW[16384];
  for (int i = threadIdx.x*4; i < 16384; i += 1024)
    *(float4*)&sW[i] = *(const float4*)&wbig[i];
  __syncthreads();
  int lane = threadIdx.x & 63;
  int wid = __builtin_amdgcn_readfirstlane(threadIdx.x >> 6);
  int vb = blockIdx.x*32 + wid*8;
  const float* ap[8];
  #pragma unroll
  for (int j = 0; j < 8; ++j){
    int vj = vb + j; if (vj > n-1) vj = n-1;
    ap[j] = accx + (size_t)vj*256;
  }
  float acc[8] = {0,0,0,0,0,0,0,0};
  for (int q = 0; q < 64; ++q){
    float w0 = sW[(q*4+0)*64 + lane];
    float w1 = sW[(q*4+1)*64 + lane];
    float w2 = sW[(q*4+2)*64 + lane];
    float w3 = sW[(q*4+3)*64 + lane];
    #pragma unroll
    for (int j = 0; j < 8; ++j){
      float4 a = *(const float4*)(ap[j] + q*4);  // uniform -> s_load_dwordx4
      acc[j] = fmaf(a.x, w0, acc[j]);
      acc[j] = fmaf(a.y, w1, acc[j]);
      acc[j] = fmaf(a.z, w2, acc[j]);
      acc[j] = fmaf(a.w, w3, acc[j]);
    }
  }
  float b = bias[lane];
  #pragma unroll
  for (int j = 0; j < 8; ++j){
    int v = vb + j;
    if (v < n){
      float o = acc[j] + b + lin[(size_t)v*64 + lane];
      if (do_relu) o = fmaxf(o, 0.f);
      outp[(size_t)v*64 + lane] = o;
    }
  }
}

extern "C" void kernel_launch(void* const* d_in, const int* in_sizes, int n_in,
                              void* d_out, int out_size, void* d_ws, size_t ws_size,
                              hipStream_t stream){
  const float* x   = (const float*)d_in[0];
  const int*   ei  = (const int*)d_in[1];
  const float* W1  = (const float*)d_in[2];
  const float* as1 = (const float*)d_in[3];
  const float* ad1 = (const float*)d_in[4];
  const float* b1  = (const float*)d_in[5];
  const float* lW1 = (const float*)d_in[6];
  const float* lb1 = (const float*)d_in[7];
  const float* W2  = (const float*)d_in[8];
  const float* as2 = (const float*)d_in[9];
  const float* ad2 = (const float*)d_in[10];
  const float* b2  = (const float*)d_in[11];
  const float* lW2 = (const float*)d_in[12];
  const float* lb2 = (const float*)d_in[13];
  int N = in_sizes[0] / 64;
  int E = in_sizes[1] / 2;
  const int* srce = ei;
  const int* dste = ei + E;

  char* w = (char*)d_ws;
  size_t off = 0;
  auto alloc = [&](size_t bytes)->char*{
    char* p = w + off; off = (off + bytes + 255) & ~(size_t)255; return p;
  };
  int*   offs   = (int*)  alloc((size_t)(N+1)*4);
  int*   deg    = (int*)  alloc((size_t)N*4);
  int*   cursor = (int*)  alloc((size_t)N*4);
  int*   blksum = (int*)  alloc(4096);
  int*   srcs   = (int*)  alloc((size_t)E*4);
  float* watt   = (float*)alloc(512*4);
  float* wbig   = (float*)alloc(16384*4);
  float* pasrc  = (float*)alloc((size_t)N*16);
  float* padst  = (float*)alloc((size_t)N*16);
  float* lin    = (float*)alloc((size_t)N*256);
  float* hbuf   = (float*)alloc((size_t)N*256);
  float* accx   = (float*)alloc((size_t)N*1024);
  (void)ws_size; (void)n_in; (void)out_size;

  // CSR by destination (built once, reused by both layers)
  hipMemsetAsync(deg, 0, (size_t)N*4, stream);
  hipMemsetAsync(cursor, 0, (size_t)N*4, stream);
  int gE = (E + 255)/256;
  k_hist<<<gE, 256, 0, stream>>>(dste, deg, E);
  int nelem = N + 1;
  int nb = (nelem + 255)/256;
  k_scan_local<<<nb, 256, 0, stream>>>(deg, offs, blksum, nelem, N);
  k_scan_blk<<<1, 256, 0, stream>>>(blksum, nb);
  k_scan_add<<<nb, 256, 0, stream>>>(offs, blksum, nelem);
  k_scatter<<<gE, 256, 0, stream>>>(srce, dste, offs, cursor, srcs, E);

  int gATT  = (N*8 + 255)/256;
  int ntile = (N + 31)/32;
  int gAGG  = (N + 3)/4;
  float* outp = (float*)d_out;

  // ----- layer 1 -----
  k_prep<<<1, 512, 0, stream>>>(W1, as1, ad1, watt, wbig);
  k_att <<<gATT, 256, 0, stream>>>(x, watt, pasrc, padst, N);
  k_lin <<<ntile, 256, 0, stream>>>(x, lW1, lb1, lin, N);
  k_agg <<<gAGG, 256, 0, stream>>>(x, pasrc, padst, offs, srcs, accx, N);
  k_out <<<ntile, 256, 0, stream>>>(accx, wbig, b1, lin, hbuf, N, 1);

  // ----- layer 2 -----
  k_prep<<<1, 512, 0, stream>>>(W2, as2, ad2, watt, wbig);
  k_att <<<gATT, 256, 0, stream>>>(hbuf, watt, pasrc, padst, N);
  k_lin <<<ntile, 256, 0, stream>>>(hbuf, lW2, lb2, lin, N);
  k_agg <<<gAGG, 256, 0, stream>>>(hbuf, pasrc, padst, offs, srcs, accx, N);
  k_out <<<ntile, 256, 0, stream>>>(accx, wbig, b2, lin, outp, N, 0);
}